// Round 1
// baseline (1447.973 us; speedup 1.0000x reference)
//
#include <hip/hip_runtime.h>

#define N_CHR 50000
#define E_CHR 500000
#define N_SLV 30000
#define E_SLV 300000
#define BATCH_B 256
#define FEAT 64
#define DIM 128
#define HALF 64
#define ENSN 3

// ---------------- CSR build ----------------

__global__ void hist_k(const int* __restrict__ dst, int* __restrict__ cnt, int E) {
    int i = blockIdx.x * blockDim.x + threadIdx.x;
    int stride = gridDim.x * blockDim.x;
    for (; i < E; i += stride) atomicAdd(&cnt[dst[i]], 1);
}

// single-block exclusive scan, writes off[0..n] (off[n] = total)
__global__ void scan_excl_k(const int* __restrict__ cnt, int* __restrict__ off, int n) {
    __shared__ int sdata[1024];
    __shared__ int carry;
    int tid = threadIdx.x;
    if (tid == 0) carry = 0;
    __syncthreads();
    for (int base = 0; base < n; base += 1024) {
        int i = base + tid;
        int v = (i < n) ? cnt[i] : 0;
        sdata[tid] = v;
        __syncthreads();
        for (int ofs = 1; ofs < 1024; ofs <<= 1) {
            int t = (tid >= ofs) ? sdata[tid - ofs] : 0;
            __syncthreads();
            sdata[tid] += t;
            __syncthreads();
        }
        if (i < n) off[i] = carry + sdata[tid] - v;
        __syncthreads();
        if (tid == 0) carry += sdata[1023];
        __syncthreads();
    }
    if (tid == 0) off[n] = carry;
}

__global__ void fill_k(const int* __restrict__ src, const int* __restrict__ dst,
                       int E, int* __restrict__ cursor, int* __restrict__ csr) {
    int i = blockIdx.x * blockDim.x + threadIdx.x;
    int stride = gridDim.x * blockDim.x;
    for (; i < E; i += stride) {
        int p = atomicAdd(&cursor[dst[i]], 1);
        csr[p] = src[i];
    }
}

// ---------------- pull aggregation: Y[i,:] = sum_{j in in(i)} H[csr[j],:] ----------------

template<int F, bool RELU>
__global__ void agg_k(const float* __restrict__ H, const int* __restrict__ off,
                      const int* __restrict__ csr, float* __restrict__ Y) {
    int i = blockIdx.x;
    int f = threadIdx.x;               // F threads
    int s = off[i], e2 = off[i + 1];
    float acc = 0.f;
    int j = s;
    for (; j + 1 < e2; j += 2) {       // unroll-2: two gathers in flight
        int s0 = csr[j], s1 = csr[j + 1];
        acc += H[s0 * F + f];
        acc += H[s1 * F + f];
    }
    if (j < e2) acc += H[csr[j] * F + f];
    Y[i * F + f] = RELU ? fmaxf(acc, 0.f) : acc;
}

// ---------------- node-row GEMM: Y[n, 0:COLS] = X[n, 0:K] @ W[K, COLS] ----------------

template<int K, int COLS, int TM, bool RELU>
__global__ void gemm_k(const float* __restrict__ X, const float* __restrict__ W,
                       float* __restrict__ Y, int n) {
    __shared__ float xs[TM][K];
    int base = blockIdx.x * TM;
    int c = threadIdx.x;               // COLS threads
    for (int i = c; i < TM * K; i += COLS) {
        int m = i / K, k = i - m * K;
        int node = base + m;
        xs[m][k] = (node < n) ? X[node * K + k] : 0.f;
    }
    __syncthreads();
    float acc[TM];
#pragma unroll
    for (int m = 0; m < TM; m++) acc[m] = 0.f;
    for (int k = 0; k < K; k++) {
        float w = W[k * COLS + c];     // coalesced; W tile stays hot in L1/L2
#pragma unroll
        for (int m = 0; m < TM; m++) acc[m] = fmaf(xs[m][k], w, acc[m]);  // xs broadcast
    }
#pragma unroll
    for (int m = 0; m < TM; m++) {
        int node = base + m;
        if (node < n) {
            float v = acc[m];
            Y[node * COLS + c] = RELU ? fmaxf(v, 0.f) : v;
        }
    }
}

// ---------------- global_add_pool via atomics into rep[B, 2*ENS*HALF] ----------------

__global__ void pool_k(const float* __restrict__ H, const int* __restrict__ batch,
                       float* __restrict__ rep, int colOff) {
    int i = blockIdx.x;
    int f = threadIdx.x;               // HALF=64 threads
    atomicAdd(&rep[batch[i] * (2 * ENSN * HALF) + colOff + f], H[i * HALF + f]);
}

// ---------------- projection heads -> hg[B, 2*ENS*DIM] ----------------

__global__ void head_k(const float* __restrict__ rep,
                       const float* __restrict__ cW, const float* __restrict__ cB,
                       const float* __restrict__ sW, const float* __restrict__ sB,
                       float* __restrict__ hg) {
    int b = blockIdx.x;
    int be = blockIdx.y;               // 0..2 chr ens, 3..5 slv ens
    int branch = be / ENSN, e = be % ENSN;
    int c = threadIdx.x;               // DIM=128 threads
    __shared__ float r[HALF];
    const float* repRow = rep + b * (2 * ENSN * HALF) + branch * (ENSN * HALF) + e * HALF;
    if (c < HALF) r[c] = repRow[c];
    __syncthreads();
    const float* W = (branch ? sW : cW) + e * HALF * DIM;
    const float* Bv = (branch ? sB : cB) + e * DIM;
    float acc = Bv[c];
#pragma unroll
    for (int k = 0; k < HALF; k++) acc = fmaf(r[k], W[k * DIM + c], acc);
    hg[b * (2 * ENSN * DIM) + branch * (ENSN * DIM) + e * DIM + c] = fmaxf(acc, 0.f);
}

// ---------------- final MLP: out[b] = (relu(hg@fc1+b1)) @ fc2 + b2 ----------------

__global__ void final_k(const float* __restrict__ hg, const float* __restrict__ W1,
                        const float* __restrict__ b1, const float* __restrict__ W2,
                        const float* __restrict__ b2, float* __restrict__ out) {
    int b = blockIdx.x;
    int c = threadIdx.x;               // 128 threads
    const int IN = 2 * ENSN * DIM;     // 768
    __shared__ float row[2 * ENSN * DIM];
    for (int i = c; i < IN; i += DIM) row[i] = hg[b * IN + i];
    __syncthreads();
    float acc = b1[c];
    for (int k = 0; k < IN; k++) acc = fmaf(row[k], W1[k * DIM + c], acc);
    acc = fmaxf(acc, 0.f);
    __shared__ float red[DIM];
    red[c] = acc * W2[c];
    __syncthreads();
    for (int s = DIM / 2; s > 0; s >>= 1) {
        if (c < s) red[c] += red[c + s];
        __syncthreads();
    }
    if (c == 0) out[b] = red[0] + b2[0];
}

// ---------------- host ----------------

extern "C" void kernel_launch(void* const* d_in, const int* in_sizes, int n_in,
                              void* d_out, int out_size, void* d_ws, size_t ws_size,
                              hipStream_t stream) {
    const float* chr_x = (const float*)d_in[0];
    const float* slv_x = (const float*)d_in[1];
    const int* chr_ei = (const int*)d_in[2];   // [2, E_CHR]: row0 src, row1 dst
    const int* slv_ei = (const int*)d_in[3];
    const int* chr_batch = (const int*)d_in[4];
    const int* slv_batch = (const int*)d_in[5];
    const float* chr_W0 = (const float*)d_in[6];
    const float* chr_W1 = (const float*)d_in[7];
    const float* chr_W2 = (const float*)d_in[8];
    const float* slv_W0 = (const float*)d_in[9];
    const float* slv_W1 = (const float*)d_in[10];
    const float* slv_W2 = (const float*)d_in[11];
    const float* cfc_W = (const float*)d_in[12];
    const float* cfc_b = (const float*)d_in[13];
    const float* sfc_W = (const float*)d_in[14];
    const float* sfc_b = (const float*)d_in[15];
    const float* fc1_W = (const float*)d_in[16];
    const float* fc1_b = (const float*)d_in[17];
    const float* fc2_W = (const float*)d_in[18];
    const float* fc2_b = (const float*)d_in[19];
    float* out = (float*)d_out;

    // workspace carve-up (256B aligned)
    char* w = (char*)d_ws;
    auto carve = [&](size_t bytes) {
        void* p = (void*)w;
        w += (bytes + 255) & ~(size_t)255;
        return p;
    };
    int* off_chr = (int*)carve((N_CHR + 1) * sizeof(int));
    int* csr_chr = (int*)carve((size_t)E_CHR * sizeof(int));
    int* off_slv = (int*)carve((N_SLV + 1) * sizeof(int));
    int* csr_slv = (int*)carve((size_t)E_SLV * sizeof(int));
    int* cursor  = (int*)carve((size_t)N_CHR * sizeof(int));
    float* aggX  = (float*)carve((size_t)N_CHR * FEAT * sizeof(float));
    float* bufA  = (float*)carve((size_t)N_CHR * DIM * sizeof(float));
    float* bufB  = (float*)carve((size_t)N_CHR * DIM * sizeof(float));
    float* rep   = (float*)carve((size_t)BATCH_B * 2 * ENSN * HALF * sizeof(float));
    float* hg    = (float*)carve((size_t)BATCH_B * 2 * ENSN * DIM * sizeof(float));

    // ---- CSR build (chr) ----
    hipMemsetAsync(cursor, 0, N_CHR * sizeof(int), stream);
    hist_k<<<512, 256, 0, stream>>>(chr_ei + E_CHR, cursor, E_CHR);
    scan_excl_k<<<1, 1024, 0, stream>>>(cursor, off_chr, N_CHR);
    hipMemcpyAsync(cursor, off_chr, N_CHR * sizeof(int), hipMemcpyDeviceToDevice, stream);
    fill_k<<<512, 256, 0, stream>>>(chr_ei, chr_ei + E_CHR, E_CHR, cursor, csr_chr);

    // ---- CSR build (slv) ----
    hipMemsetAsync(cursor, 0, N_SLV * sizeof(int), stream);
    hist_k<<<512, 256, 0, stream>>>(slv_ei + E_SLV, cursor, E_SLV);
    scan_excl_k<<<1, 1024, 0, stream>>>(cursor, off_slv, N_SLV);
    hipMemcpyAsync(cursor, off_slv, N_SLV * sizeof(int), hipMemcpyDeviceToDevice, stream);
    fill_k<<<512, 256, 0, stream>>>(slv_ei, slv_ei + E_SLV, E_SLV, cursor, csr_slv);

    hipMemsetAsync(rep, 0, (size_t)BATCH_B * 2 * ENSN * HALF * sizeof(float), stream);

    // ---- chr branch ----
    // layer-1 rewrite: agg(x) once (shared across ensembles), then GEMM per ens
    agg_k<FEAT, false><<<N_CHR, FEAT, 0, stream>>>(chr_x, off_chr, csr_chr, aggX);
    for (int e = 0; e < ENSN; e++) {
        gemm_k<FEAT, DIM, 16, true><<<(N_CHR + 15) / 16, DIM, 0, stream>>>(
            aggX, chr_W0 + (size_t)e * FEAT * DIM, bufA, N_CHR);                 // h1 = relu(aggX@W0)
        agg_k<DIM, false><<<N_CHR, DIM, 0, stream>>>(bufA, off_chr, csr_chr, bufB);  // a1 = agg(h1)
        gemm_k<DIM, DIM, 16, true><<<(N_CHR + 15) / 16, DIM, 0, stream>>>(
            bufB, chr_W1 + (size_t)e * DIM * DIM, bufA, N_CHR);                  // h2 = relu(a1@W1)
        gemm_k<DIM, HALF, 16, false><<<(N_CHR + 15) / 16, HALF, 0, stream>>>(
            bufA, chr_W2 + (size_t)e * DIM * HALF, bufB, N_CHR);                 // p3 = h2@W2
        agg_k<HALF, true><<<N_CHR, HALF, 0, stream>>>(bufB, off_chr, csr_chr, bufA); // h3 = relu(agg(p3))
        pool_k<<<N_CHR, HALF, 0, stream>>>(bufA, chr_batch, rep, e * HALF);
    }

    // ---- slv branch ----
    agg_k<FEAT, false><<<N_SLV, FEAT, 0, stream>>>(slv_x, off_slv, csr_slv, aggX);
    for (int e = 0; e < ENSN; e++) {
        gemm_k<FEAT, DIM, 16, true><<<(N_SLV + 15) / 16, DIM, 0, stream>>>(
            aggX, slv_W0 + (size_t)e * FEAT * DIM, bufA, N_SLV);
        agg_k<DIM, false><<<N_SLV, DIM, 0, stream>>>(bufA, off_slv, csr_slv, bufB);
        gemm_k<DIM, DIM, 16, true><<<(N_SLV + 15) / 16, DIM, 0, stream>>>(
            bufB, slv_W1 + (size_t)e * DIM * DIM, bufA, N_SLV);
        gemm_k<DIM, HALF, 16, false><<<(N_SLV + 15) / 16, HALF, 0, stream>>>(
            bufA, slv_W2 + (size_t)e * DIM * HALF, bufB, N_SLV);
        agg_k<HALF, true><<<N_SLV, HALF, 0, stream>>>(bufB, off_slv, csr_slv, bufA);
        pool_k<<<N_SLV, HALF, 0, stream>>>(bufA, slv_batch, rep, ENSN * HALF + e * HALF);
    }

    // ---- heads + final MLP ----
    head_k<<<dim3(BATCH_B, 2 * ENSN), DIM, 0, stream>>>(rep, cfc_W, cfc_b, sfc_W, sfc_b, hg);
    final_k<<<BATCH_B, DIM, 0, stream>>>(hg, fc1_W, fc1_b, fc2_W, fc2_b, out);
}